// Round 10
// baseline (302.530 us; speedup 1.0000x reference)
//
#include <hip/hip_runtime.h>

#define HH 512
#define WW 512
#define HW_ 262144
#define NIMG 16
#define MK 2048
#define CAPB 4096
#define SCAP 32768   // survivor capacity per image
#define SBUFN 768    // per-block survivor staging (>=484 worst-case maxima per 64x64 tile)

static constexpr size_t OFF_B1    = 16777216;   // 16MB
static constexpr size_t OFF_SMALL = 50331648;   // 48MB
// regions inside buffer A (all written only after A's last read in k_smwnms):
static constexpr size_t OFF_SEL  = 4194304;
static constexpr size_t OFF_BND  = 4325376;
static constexpr size_t OFF_PP   = 4849664;
static constexpr size_t OFF_WXp  = 5111808;
static constexpr size_t OFF_WYp  = 5242880;
static constexpr size_t OFF_LG   = 5373952;
static constexpr size_t OFF_SL   = 5505024;
static constexpr size_t OFF_PMIN = 5636096;
// regions inside B12's upper half (dead after k_match):
static constexpr size_t OFF_HIST = 33554432;            // 4MB
static constexpr size_t OFF_SURV = 33554432 + 4194304;  // 4MB

// per-image counters padded to 128B to kill cacheline serialization
#define CSTRIDE 32

// ---------- helpers ----------
__device__ __forceinline__ float wred64(float v) {
  for (int m = 1; m < 64; m <<= 1) v += __shfl_xor(v, m);
  return v;
}

__device__ __forceinline__ float coh_loadf(const float* p) {
  return __hip_atomic_load(p, __ATOMIC_RELAXED, __HIP_MEMORY_SCOPE_AGENT);
}

__device__ __forceinline__ void g25_wave0(float* g) {
  int t = threadIdx.x;
  if (t < 64) {
    float raw = 0.0f;
    if (t < 25) {
      float x = -1.0f + (float)t * (2.0f / 24.0f);
      raw = expf(-(x * x) / 0.5f);
    }
    float s = raw;
    for (int m = 1; m < 64; m <<= 1) s += __shfl_xor(s, m);
    if (t < 25) g[t] = raw / s;
  }
}
__device__ __forceinline__ void w51_wave0(float* wc) {
  int t = threadIdx.x;
  if (t < 51) {
    float x = -2.0f + (float)t * (4.0f / 50.0f);
    wc[t] = expf(-x * x);
  }
}

// ---------- pass 1: exp + all three global sums (separable conv trick) ----------
// tap-range sums via prefix differences (gp[hi+1]-gp[lo]) instead of per-thread loops
__global__ void __launch_bounds__(256)
k_pre(const float* __restrict__ x, const float* __restrict__ hd, float* A,
      float* sume, float* sumS, float* Zb) {
  __shared__ float g[25];
  __shared__ float gp[26];
  __shared__ float red[12];
  int tid = threadIdx.x;
  g25_wave0(g);
  if (tid == 0) {
    float c = 0.0f;
    gp[0] = 0.0f;
    for (int k = 0; k < 25; k++) { c += g[k]; gp[k + 1] = c; }
  }
  size_t base = (size_t)blockIdx.x * 1024;
  size_t e = base + tid * 4;
  float4 xs = *(const float4*)(x + e);
  float4 hs = *(const float4*)(hd + e);
  __syncthreads();
  int rem = (int)(e & (HW_ - 1));
  int y = rem >> 9, x0 = rem & 511;
  float wv;
  {
    int k0 = y - 499; if (k0 < 0) k0 = 0;
    int k1 = y + 12;  if (k1 > 24) k1 = 24;
    wv = gp[k1 + 1] - gp[k0];
  }
  float cwv[4], cpv[4];
#pragma unroll
  for (int q = 0; q < 4; q++) {
    int i = x0 + q;
    int lo = i - 487; if (lo < 0) lo = 0;
    int hi = i;       if (hi > 24) hi = 24;
    cwv[q] = gp[hi + 1] - gp[lo];
    int lo2 = i - 499; if (lo2 < 0) lo2 = 0;
    int hi2 = i + 12;  if (hi2 > 24) hi2 = 24;
    cpv[q] = gp[hi2 + 1] - gp[lo2];
  }
  float e0 = expf(xs.x), e1 = expf(xs.y), e2 = expf(xs.z), e3 = expf(xs.w);
  *(float4*)(A + e) = make_float4(e0, e1, e2, e3);
  float r0 = (e0 + e1) + (e2 + e3);
  float r1 = (e0 * cwv[0] + e1 * cwv[1] + e2 * cwv[2] + e3 * cwv[3]) * wv;
  float r2 = (hs.x * cpv[0] + hs.y * cpv[1] + hs.z * cpv[2] + hs.w * cpv[3]) * wv;
  r0 = wred64(r0); r1 = wred64(r1); r2 = wred64(r2);
  int wid = tid >> 6;
  if ((tid & 63) == 0) { red[wid] = r0; red[4 + wid] = r1; red[8 + wid] = r2; }
  __syncthreads();
  if (tid == 0) {
    int img = (int)(base >> 18);
    atomicAdd(&sume[img * CSTRIDE], red[0] + red[1] + red[2] + red[3]);
    atomicAdd(&sumS[img * CSTRIDE], red[4] + red[5] + red[6] + red[7]);
    atomicAdd(&Zb[img * CSTRIDE], red[8] + red[9] + red[10] + red[11]);
  }
}

// ---------- horizontal convs: pure streaming, one row per block ----------
// writes interleaved {b1,b2} pairs -> single dwordx4 store per thread
__global__ void __launch_bounds__(256)
k_hconv(const float* __restrict__ A, const float* __restrict__ hd,
        const float* __restrict__ sume, float* b12) {
  __shared__ __align__(16) float ta[512];
  __shared__ __align__(16) float th[536];
  __shared__ float g[25];
  int tid = threadIdx.x;
  int blk = blockIdx.x;
  int img = blk >> 9;
  size_t rowoff = (size_t)blk * 512;
  g25_wave0(g);
  ((float2*)ta)[tid] = *(const float2*)(A + rowoff + tid * 2);
  ((float2*)(th + 12))[tid] = *(const float2*)(hd + rowoff + tid * 2);
  if (tid < 12) { th[tid] = 0.0f; th[524 + tid] = 0.0f; }
  __syncthreads();
  float inv = 1.0f / sume[img * CSTRIDE];
  int j = 2 * tid;
  float v1a = 0.0f, v1b = 0.0f;
  if (tid >= 6 && tid <= 249) {
    float w[26];
#pragma unroll
    for (int d = 0; d < 26; d++) w[d] = ta[j - 12 + d];
#pragma unroll
    for (int d = 0; d < 25; d++) {
      v1a = fmaf(g[d], w[d], v1a);
      v1b = fmaf(g[d], w[d + 1], v1b);
    }
  }
  float v2a = 0.0f, v2b = 0.0f;
  {
    float u[26];
#pragma unroll
    for (int d = 0; d < 26; d++) u[d] = th[j + d];
#pragma unroll
    for (int d = 0; d < 25; d++) {
      v2a = fmaf(g[d], u[d], v2a);
      v2b = fmaf(g[d], u[d + 1], v2b);
    }
  }
  // pixel pair (j, j+1): interleaved {b1,b2} per pixel
  *(float4*)(b12 + (rowoff + j) * 2) =
      make_float4(v1a * inv, v2a, v1b * inv, v2b);
}

// fused vertical convs + KL reduction — global-direct column conv.
// Each thread owns one column x 16 output rows; the 25-tap window slides
// down the column in registers (rolling 16-reg weight window, zero-padded
// taps keep fmaf order bit-identical to the tiled version). No LDS tile.
__global__ void __launch_bounds__(256)
k_match(const float* __restrict__ b12,
        const float* __restrict__ sume, const float* sumS, const float* Zb,
        float* macc) {
  __shared__ float g[40];                      // taps 0..24 real, 25..39 = 0
  __shared__ float red4[4];
  int tid = threadIdx.x;
  g25_wave0(g);
  if (tid >= 25 && tid < 40) g[tid] = 0.0f;
  int blk = blockIdx.x;
  int img = blk >> 6;
  int ty = (blk >> 3) & 7;
  int tx = blk & 7;
  int y0 = ty * 64, x0 = tx * 64;
  const float* base12 = b12 + (size_t)img * HW_ * 2;
  float Z = Zb[img * CSTRIDE];
  float invs = 1.0f / sume[img * CSTRIDE];
  float logS = logf(sumS[img * CSTRIDE] * invs + (float)HW_ * 1e-8f);
  __syncthreads();
  int seg = tid >> 6;        // 4 row segments of 16
  int c = tid & 63;
  int r0 = seg * 16;
  const float* colp = base12 + (size_t)(x0 + c) * 2;
  float s[16], d[16], wreg[16];
#pragma unroll
  for (int jj = 0; jj < 16; jj++) { s[jj] = 0.f; d[jj] = 0.f; wreg[jj] = 0.f; }
  int ybase = y0 + r0 - 12;
#pragma unroll
  for (int i = 0; i < 40; i++) {
    int y = ybase + i;
    float vx = 0.0f, vy = 0.0f;
    if ((unsigned)y < 512u) {                   // wave-uniform
      float2 v = *(const float2*)(colp + (size_t)y * 1024);
      vx = v.x; vy = v.y;
    }
#pragma unroll
    for (int jj = 15; jj >= 1; jj--) wreg[jj] = wreg[jj - 1];
    wreg[0] = g[i];
#pragma unroll
    for (int jj = 0; jj < 16; jj++) {
      s[jj] = fmaf(wreg[jj], vx, s[jj]);
      d[jj] = fmaf(wreg[jj], vy, d[jj]);
    }
  }
  float acc = 0.0f;
#pragma unroll
  for (int jj = 0; jj < 16; jj++) {
    float p = d[jj] / Z;
    if (p > 0.0f)
      acc += p * (logf(fmaxf(p, 1e-30f)) - (logf(s[jj] + 1e-8f) - logS));
  }
  acc = wred64(acc);
  if ((tid & 63) == 0) red4[tid >> 6] = acc;
  __syncthreads();
  if (tid == 0)
    atomicAdd(macc, red4[0] + red4[1] + red4[2] + red4[3]);
}

// ---------- keypoint sampling ----------
// also zeroes 512B of hist per block (replaces the 4MB memset dispatch)
__global__ void __launch_bounds__(256)
k_h51(const float* __restrict__ A, const float* __restrict__ sume, float* out,
      unsigned* __restrict__ hist) {
  __shared__ float wc[51];
  __shared__ __align__(16) float ta[564];
  int tid = threadIdx.x;
  int blk = blockIdx.x;
  int img = blk >> 9;
  size_t rowoff = (size_t)blk * 512;
  w51_wave0(wc);
  if (tid < 32)
    ((uint4*)hist)[(size_t)blk * 32 + tid] = make_uint4(0u, 0u, 0u, 0u);
  float s1 = 1e4f / sume[img * CSTRIDE];
  for (int i = tid; i < 562; i += 256) {
    int j = i - 25;
    ta[i] = ((unsigned)j < 512u) ? fmaf(A[rowoff + j], s1, 1e-2f) : 0.0f;
  }
  __syncthreads();
  int j = 2 * tid;
  float w[52];
#pragma unroll
  for (int d = 0; d < 52; d++) w[d] = ta[j + d];
  float va = 0.0f, vb = 0.0f;
#pragma unroll
  for (int d = 0; d < 51; d++) {
    va = fmaf(wc[d], w[d], va);
    vb = fmaf(wc[d], w[d + 1], vb);
  }
  ((float2*)out)[blk * 256 + tid] = make_float2(va, vb);
}

// fused: vertical 51-tap (register-tiled R=3 x C=4, float4 LDS) + coverage
// reweight + separable 5x5 NMS (float4) + block-aggregated survivor
// compaction + histogram.  [R2/R4/R9-proven version: ~49us, 40 VGPR, no spill]
__global__ void __launch_bounds__(512, 6)
k_smwnms(const float* __restrict__ A, const float* __restrict__ sume,
         const float* __restrict__ b1,
         unsigned long long* surv, unsigned* scnt, unsigned* hist) {
  __shared__ float wc[53];                     // taps 0..50 real, 51..52 = 0
  __shared__ __align__(16) float tb1[119 * 68];
  __shared__ __align__(16) float tsm[68 * 68];
  __shared__ unsigned lcnt;
  __shared__ unsigned gbase;
  float* hm = tb1;  // alias: tb1 dead after conv phase; hm is 68x64 = floats [0,4352)
  unsigned long long* sbuf = (unsigned long long*)(tb1 + 4352);
  int tid = threadIdx.x;
  w51_wave0(wc);
  if (tid == 51 || tid == 52) wc[tid] = 0.0f;
  if (tid == 0) lcnt = 0;
  int blk = blockIdx.x;
  int img = blk >> 6;
  int ty = (blk >> 3) & 7;
  int tx = blk & 7;
  int y0 = ty * 64, x0 = tx * 64;
  const float* base = b1 + (size_t)img * HW_;
  {
    float2 vreg[8];
    int laddr[8];
#pragma unroll
    for (int k = 0; k < 8; k++) {
      int i = tid + k * 512;
      bool ok = (i < 119 * 34);
      int r = i / 34, c2 = i - r * 34;
      int y = y0 + r - 27;
      int x = x0 + c2 * 2 - 2;
      float2 v = make_float2(0.0f, 0.0f);
      if (ok && (unsigned)y < 512u && (unsigned)x < 512u)
        v = *(const float2*)(base + (size_t)y * 512 + x);
      vreg[k] = v;
      laddr[k] = ok ? (r * 68 + c2 * 2) : -1;
    }
#pragma unroll
    for (int k = 0; k < 8; k++)
      if (laddr[k] >= 0) *(float2*)(tb1 + laddr[k]) = vreg[k];
  }
  __syncthreads();
  float inv = 1.0f / sume[img * CSTRIDE];
  const float* abase = A + (size_t)img * HW_;
  if (tid < 23 * 17) {
    int rg = tid / 17, cg = tid - rg * 17;
    int r0 = rg * 3, c0 = cg * 4;
    int nr = (r0 <= 65) ? 3 : 2;  // rg=22 -> output rows 66,67 only
    float2 apre[3][2];
#pragma unroll
    for (int jj = 0; jj < 3; jj++) {
      int y = y0 + r0 + jj - 2;
      int xb = x0 + c0 - 2;
      apre[jj][0] = make_float2(0.f, 0.f);
      apre[jj][1] = make_float2(0.f, 0.f);
      if ((unsigned)y < 512u) {
        const float* ar = abase + (size_t)y * 512;
        if ((unsigned)xb < 512u) apre[jj][0] = *(const float2*)(ar + xb);
        if ((unsigned)(xb + 2) < 512u) apre[jj][1] = *(const float2*)(ar + xb + 2);
      }
    }
    float a0x = 0.f, a0y = 0.f, a0z = 0.f, a0w = 0.f;
    float a1x = 0.f, a1y = 0.f, a1z = 0.f, a1w = 0.f;
    float a2x = 0.f, a2y = 0.f, a2z = 0.f, a2w = 0.f;
    float w1 = 0.f, w2 = 0.f;
    const float* tp = tb1 + r0 * 68 + c0;
#pragma unroll 4
    for (int i = 0; i < 53; i++) {
      float4 v = *(const float4*)(tp + i * 68);
      float w0 = wc[i];
      a0x = fmaf(w0, v.x, a0x); a0y = fmaf(w0, v.y, a0y);
      a0z = fmaf(w0, v.z, a0z); a0w = fmaf(w0, v.w, a0w);
      a1x = fmaf(w1, v.x, a1x); a1y = fmaf(w1, v.y, a1y);
      a1z = fmaf(w1, v.z, a1z); a1w = fmaf(w1, v.w, a1w);
      a2x = fmaf(w2, v.x, a2x); a2y = fmaf(w2, v.y, a2y);
      a2z = fmaf(w2, v.z, a2z); a2w = fmaf(w2, v.w, a2w);
      w2 = w1; w1 = w0;
    }
    auto storerow = [&](int jj, float ax, float ay, float az, float aw,
                        float2 p0, float2 p1) {
      int r = r0 + jj;
      int y = y0 + r - 2;
      int xb = x0 + c0 - 2;
      float4 res = make_float4(-3.4e38f, -3.4e38f, -3.4e38f, -3.4e38f);
      if ((unsigned)y < 512u) {
        if ((unsigned)xb < 512u) {
          res.x = (p0.x * inv) / sqrtf(ax + 1e-8f);
          res.y = (p0.y * inv) / sqrtf(ay + 1e-8f);
        }
        if ((unsigned)(xb + 2) < 512u) {
          res.z = (p1.x * inv) / sqrtf(az + 1e-8f);
          res.w = (p1.y * inv) / sqrtf(aw + 1e-8f);
        }
      }
      *(float4*)(tsm + r * 68 + c0) = res;
    };
    storerow(0, a0x, a0y, a0z, a0w, apre[0][0], apre[0][1]);
    storerow(1, a1x, a1y, a1z, a1w, apre[1][0], apre[1][1]);
    if (nr == 3) storerow(2, a2x, a2y, a2z, a2w, apre[2][0], apre[2][1]);
  }
  __syncthreads();
  for (int i = tid; i < 68 * 16; i += 512) {
    int r = i >> 4, cg = i & 15;
    const float* row = tsm + r * 68 + cg * 4;
    float4 v0 = *(const float4*)(row);
    float4 v1 = *(const float4*)(row + 4);
    float p01 = fmaxf(v0.x, v0.y), p12 = fmaxf(v0.y, v0.z);
    float p23 = fmaxf(v0.z, v0.w), p34 = fmaxf(v0.w, v1.x);
    float p45 = fmaxf(v1.x, v1.y), p56 = fmaxf(v1.y, v1.z);
    float m0 = fmaxf(fmaxf(p01, p23), v1.x);
    float m1 = fmaxf(fmaxf(p12, p34), v1.y);
    float m2 = fmaxf(fmaxf(p23, p45), v1.z);
    float m3 = fmaxf(fmaxf(p34, p56), v1.w);
    *(float4*)(hm + r * 64 + cg * 4) = make_float4(m0, m1, m2, m3);
  }
  __syncthreads();
  for (int k0 = 0; k0 < 2; k0++) {
    int i = tid + k0 * 512;
    int r = i >> 4, cb = (i & 15) * 4;
    const float* tp2 = tsm + (r + 2) * 68 + cb + 2;
    float2 va = *(const float2*)(tp2);
    float2 vb = *(const float2*)(tp2 + 2);
    float4 m0 = *(const float4*)(hm + r * 64 + cb);
    float4 m1 = *(const float4*)(hm + (r + 1) * 64 + cb);
    float4 m2 = *(const float4*)(hm + (r + 2) * 64 + cb);
    float4 m3 = *(const float4*)(hm + (r + 3) * 64 + cb);
    float4 m4 = *(const float4*)(hm + (r + 4) * 64 + cb);
    float Mx = fmaxf(fmaxf(m0.x, m1.x), fmaxf(fmaxf(m2.x, m3.x), m4.x));
    float My = fmaxf(fmaxf(m0.y, m1.y), fmaxf(fmaxf(m2.y, m3.y), m4.y));
    float Mz = fmaxf(fmaxf(m0.z, m1.z), fmaxf(fmaxf(m2.z, m3.z), m4.z));
    float Mw = fmaxf(fmaxf(m0.w, m1.w), fmaxf(fmaxf(m2.w, m3.w), m4.w));
    auto keepf = [&](float vk, float Mk, int k) {
      if (vk == Mk && vk != 0.0f) {
        unsigned p = atomicAdd(&lcnt, 1u);   // LDS atomic: cheap
        unsigned bits = __float_as_uint(vk);
        unsigned idx = (unsigned)((y0 + r) * 512 + x0 + cb + k);
        if (p < SBUFN)
          sbuf[p] = ((unsigned long long)bits << 32) |
                    (unsigned long long)(idx ^ 0xFFFFFFFFu);
        atomicAdd(&hist[(size_t)img * 65536 + (bits >> 16)], 1u);
      }
    };
    keepf(va.x, Mx, 0); keepf(va.y, My, 1);
    keepf(vb.x, Mz, 2); keepf(vb.y, Mw, 3);
  }
  __syncthreads();
  unsigned total = lcnt; if (total > SBUFN) total = SBUFN;
  if (tid == 0) gbase = atomicAdd(&scnt[img * CSTRIDE], total);
  __syncthreads();
  unsigned gb = gbase;
  for (unsigned i = tid; i < total; i += 512) {
    unsigned p = gb + i;
    if (p < SCAP) surv[(size_t)img * SCAP + p] = sbuf[i];
  }
}

// 1024 threads, uint4 loads, shfl-scan
__global__ void __launch_bounds__(1024)
k_thresh(const unsigned* __restrict__ hist, unsigned* Tb, unsigned* needb) {
  int img = blockIdx.x;
  const unsigned* h = hist + (size_t)img * 65536;
  __shared__ unsigned wsum[16];
  __shared__ unsigned wpre[16];
  int t = threadIdx.x;  // thread t covers bins 65535-(t*64) .. 65472-(t*64)
  int b0 = 65472 - 64 * t;  // lowest bin of chunk (16B aligned)
  const uint4* hv = (const uint4*)(h + b0);
  unsigned s = 0;
#pragma unroll
  for (int k = 0; k < 16; k++) {
    uint4 u = hv[k];
    s += u.x + u.y + u.z + u.w;
  }
  if (b0 == 0) s += 0x00100000u - h[0];  // bin0 sentinel
  // inclusive wave scan over t (ascending t == descending bins)
  unsigned inc = s;
  for (int m = 1; m < 64; m <<= 1) {
    unsigned o = __shfl_up(inc, m);
    if ((t & 63) >= m) inc += o;
  }
  if ((t & 63) == 63) wsum[t >> 6] = inc;
  __syncthreads();
  if (t < 16) {
    unsigned p = 0;
    for (int k = 0; k < 16; k++) if (k < t) p += wsum[k];
    wpre[t] = p;
  }
  __syncthreads();
  unsigned pre = wpre[t >> 6] + inc - s;  // exclusive prefix of this chunk
  if (pre < MK && pre + s >= MK) {
    unsigned c = pre;
    for (int k = 0; k < 64; k++) {
      int bin = 65535 - (t * 64 + k);
      unsigned cnt = (bin == 0) ? 0x00100000u : h[bin];
      if (c + cnt >= MK) { Tb[img * CSTRIDE] = (unsigned)bin; needb[img * CSTRIDE] = MK - c; break; }
      c += cnt;
    }
  }
}

// compaction from survivor list
__global__ void k_collect(const unsigned long long* __restrict__ surv,
                          const unsigned* __restrict__ scnt,
                          const unsigned* __restrict__ Tb,
                          unsigned* selcnt, unsigned* sel,
                          unsigned* bcnt, unsigned long long* bnd) {
  int blk = blockIdx.x;
  int img = blk >> 7;
  int i = (blk & 127) * 256 + threadIdx.x;
  unsigned cnt = scnt[img * CSTRIDE]; if (cnt > SCAP) cnt = SCAP;
  unsigned long long entry = ((unsigned)i < cnt) ? surv[(size_t)img * SCAP + i] : 0ull;
  unsigned bits = (unsigned)(entry >> 32);
  unsigned bin = bits >> 16;
  unsigned T = Tb[img * CSTRIDE];
  bool ok = (unsigned)i < cnt;
  bool c1 = ok && (bin > T);
  bool c2 = ok && (bin == T);
  int lane = threadIdx.x & 63;
  unsigned long long lowmask = (1ull << lane) - 1ull;

  unsigned long long m1 = __ballot(c1);
  if (m1) {
    int leader = __ffsll(m1) - 1;
    unsigned base = 0;
    if (lane == leader) base = atomicAdd(&selcnt[img * CSTRIDE], (unsigned)__popcll(m1));
    base = __shfl(base, leader);
    if (c1) {
      unsigned p = base + (unsigned)__popcll(m1 & lowmask);
      if (p < MK) sel[img * MK + p] = (unsigned)(entry & 0xFFFFFFFFull) ^ 0xFFFFFFFFu;
    }
  }
  unsigned long long m2 = __ballot(c2);
  if (m2) {
    int leader = __ffsll(m2) - 1;
    unsigned base = 0;
    if (lane == leader) base = atomicAdd(&bcnt[img * CSTRIDE], (unsigned)__popcll(m2));
    base = __shfl(base, leader);
    if (c2) {
      unsigned p = base + (unsigned)__popcll(m2 & lowmask);
      if (p < CAPB) bnd[(size_t)img * CAPB + p] = entry;
    }
  }
}

__global__ void __launch_bounds__(1024)
k_finsel(const unsigned long long* __restrict__ bnd, const unsigned* bcnt,
         const unsigned* needb, const unsigned* selcnt, unsigned* sel) {
  int img = blockIdx.x;
  __shared__ unsigned long long key[CAPB];
  unsigned bn = bcnt[img * CSTRIDE];
  int n = (bn < CAPB) ? (int)bn : CAPB;
  int np2 = 2;
  while (np2 < n) np2 <<= 1;
  int t = threadIdx.x;
  for (int k = t; k < np2; k += 1024)
    key[k] = (k < n) ? bnd[(size_t)img * CAPB + k] : 0ull;
  __syncthreads();
  for (int sz = 2; sz <= np2; sz <<= 1) {
    for (int st = sz >> 1; st > 0; st >>= 1) {
      for (int i = t; i < np2; i += 1024) {
        int l = i ^ st;
        if (l > i) {
          unsigned long long a = key[i], b = key[l];
          bool up = ((i & sz) == 0);
          if (up ? (a < b) : (a > b)) { key[i] = b; key[l] = a; }
        }
      }
      __syncthreads();
    }
  }
  unsigned c1 = selcnt[img * CSTRIDE]; if (c1 > MK) c1 = MK;
  unsigned need = needb[img * CSTRIDE];
  unsigned kk = need; if (kk > MK - c1) kk = MK - c1;
  for (unsigned m = t; m < MK - c1; m += 1024) {
    unsigned v = 0u;
    if (m < kk && m < (unsigned)n)
      v = (unsigned)(key[m] & 0xFFFFFFFFull) ^ 0xFFFFFFFFu;
    sel[img * MK + c1 + m] = v;
  }
}

// ---------- sparse loss ----------
__global__ void k_prep(const unsigned* __restrict__ sel, const float* __restrict__ scoremap,
                       const float* __restrict__ gtA, const float* __restrict__ gtB,
                       const float* __restrict__ vA, const float* __restrict__ vB,
                       float2* pp, float* wx, float* wy, float* lg, float* sl) {
  int t = blockIdx.x * 256 + threadIdx.x;  // 0..32767
  int img = t >> 11;
  unsigned idx = sel[t] & (HW_ - 1);
  int h = idx >> 9, w = idx & 511;
  pp[t] = make_float2((w + 0.5f) * (2.0f / 512.0f) - 1.0f,
                      (h + 0.5f) * (2.0f / 512.0f) - 1.0f);
  int b = (img < 8) ? img : img - 8;
  const float* gt = (img < 8) ? gtA : gtB;
  const float* vv = (img < 8) ? vA : vB;
  size_t pix = (size_t)b * HW_ + idx;
  float2 gxy = *(const float2*)(gt + pix * 4 + 2);
  wx[t] = gxy.x;
  wy[t] = gxy.y;
  lg[t] = (vv[pix] > 0.0f) ? 1.0f : 0.0f;
  sl[t] = scoremap[(size_t)img * HW_ + idx];
}

// ---------- sparse loss: mindist + (last block per image) loss ----------
// [R5-proven fusion: passed correctness, parallelism-preserving small tail]
__global__ void __launch_bounds__(256)
k_mindist(const float2* __restrict__ pp,
          const float* __restrict__ wx, const float* __restrict__ wy,
          float* pmin,
          const float* __restrict__ sl, const float* __restrict__ lg,
          float* sacc, float* macc, float* out,
          unsigned* mdone, unsigned* ldone) {
  __shared__ float2 opp[512];
  __shared__ unsigned rank_s;
  __shared__ float red[1024];
  int blk = blockIdx.x;
  int img = blk >> 5;
  int qc = (blk >> 2) & 7;
  int oc = blk & 3;
  const float2* ob = pp + (size_t)(img ^ 8) * MK + oc * 512;
  for (int k = threadIdx.x; k < 512; k += 256) opp[k] = ob[k];
  __syncthreads();
  int m = img * MK + qc * 256 + threadIdx.x;
  float ax = wx[m], ay = wy[m];
  float d[8];
#pragma unroll
  for (int u = 0; u < 8; u++) d[u] = 3.4e38f;
  for (int n = 0; n < 512; n += 8) {
#pragma unroll
    for (int u = 0; u < 8; u++) {
      float2 o = opp[n + u];
      float dx = ax - o.x, dy = ay - o.y;
      d[u] = fminf(d[u], fmaf(dx, dx, dy * dy));
    }
  }
  float d2 = fminf(fminf(fminf(d[0], d[1]), fminf(d[2], d[3])),
                   fminf(fminf(d[4], d[5]), fminf(d[6], d[7])));
  pmin[oc * (NIMG * MK) + m] = d2;
  __syncthreads();   // all 256 stores issued
  if (threadIdx.x == 0) {
    __threadfence();
    rank_s = atomicAdd(&mdone[img * CSTRIDE], 1u);
  }
  __syncthreads();
  if (rank_s != 31) return;
  __threadfence();   // acquire side
  // ---- loss for this image: emulate the 1024-leaf trees with 256 threads ----
  int t = threadIdx.x;
  const int ST = NIMG * MK;
  float l0s[4], l1s[4], s0s[4], s1s[4], g0s[4], g1s[4];
#pragma unroll
  for (int u = 0; u < 4; u++) {
    int t0 = t + u * 256;
    int i0 = img * MK + t0, i1 = i0 + 1024;
    float s0 = sl[i0], s1 = sl[i1];
    float g0 = lg[i0], g1 = lg[i1];
    s0s[u] = s0; s1s[u] = s1; g0s[u] = g0; g1s[u] = g1;
    float l0 = (g0 > 0.0f) ? s0 : -1e9f;
    float l1 = (g1 > 0.0f) ? s1 : -1e9f;
    l0s[u] = l0; l1s[u] = l1;
    red[t0] = fmaxf(l0, l1);
  }
  __syncthreads();
  for (int sd = 512; sd > 0; sd >>= 1) {
    for (int k = t; k < sd; k += 256) red[k] = fmaxf(red[k], red[k + sd]);
    __syncthreads();
  }
  float mx = red[0];
  __syncthreads();
#pragma unroll
  for (int u = 0; u < 4; u++) {
    int t0 = t + u * 256;
    red[t0] = expf(l0s[u] - mx) + expf(l1s[u] - mx);
  }
  __syncthreads();
  for (int sd = 512; sd > 0; sd >>= 1) {
    for (int k = t; k < sd; k += 256) red[k] += red[k + sd];
    __syncthreads();
  }
  float lse = mx + logf(red[0]);
  __syncthreads();
#pragma unroll
  for (int u = 0; u < 4; u++) {
    int t0 = t + u * 256;
    int i0 = img * MK + t0, i1 = i0 + 1024;
    float a = 0.0f;
    if (g0s[u] > 0.0f) {
      float mn = fminf(fminf(coh_loadf(&pmin[i0]), coh_loadf(&pmin[ST + i0])),
                       fminf(coh_loadf(&pmin[2 * ST + i0]), coh_loadf(&pmin[3 * ST + i0])));
      float r0 = expf(-100.0f * sqrtf(mn + 1e-12f));
      a += r0 * (s0s[u] - lse);
    }
    if (g1s[u] > 0.0f) {
      float mn = fminf(fminf(coh_loadf(&pmin[i1]), coh_loadf(&pmin[ST + i1])),
                       fminf(coh_loadf(&pmin[2 * ST + i1]), coh_loadf(&pmin[3 * ST + i1])));
      float r1 = expf(-100.0f * sqrtf(mn + 1e-12f));
      a += r1 * (s1s[u] - lse);
    }
    red[t0] = a;
  }
  __syncthreads();
  for (int sd = 512; sd > 0; sd >>= 1) {
    for (int k = t; k < sd; k += 256) red[k] += red[k + sd];
    __syncthreads();
  }
  float tot = red[0];
  if (t == 0) {
    atomicAdd(sacc, -tot);
    __threadfence();
    unsigned dnum = atomicAdd(ldone, 1u);
    if (dnum == NIMG - 1) {
      float sv = atomicAdd(sacc, 0.0f);   // coherent reads
      float mv = atomicAdd(macc, 0.0f);
      out[0] = sv + mv * (1.0f / 16.0f);
    }
  }
}

// ---------- launch ----------
extern "C" void kernel_launch(void* const* d_in, const int* in_sizes, int n_in,
                              void* d_out, int out_size, void* d_ws, size_t ws_size,
                              hipStream_t stream) {
  const float* scoremap = (const float*)d_in[0];
  const float* gtA = (const float*)d_in[1];
  const float* gtB = (const float*)d_in[2];
  const float* vA  = (const float*)d_in[3];
  const float* vB  = (const float*)d_in[4];
  const float* hd  = (const float*)d_in[5];

  char* ws = (char*)d_ws;
  float* A   = (float*)(ws);
  float* B12 = (float*)(ws + OFF_B1);   // interleaved {b1,b2}, 32MB [16,48)
  float* B1p = (float*)(ws + OFF_B1);   // h51 output, 16MB (after k_match)

  char* sm = ws + OFF_SMALL;
  float*    sume   = (float*)(sm + 0);
  float*    sumS   = (float*)(sm + 2048);
  float*    Zb     = (float*)(sm + 4096);
  unsigned* Tb     = (unsigned*)(sm + 6144);
  unsigned* needb  = (unsigned*)(sm + 8192);
  unsigned* selcnt = (unsigned*)(sm + 10240);
  unsigned* bcnt   = (unsigned*)(sm + 12288);
  float*    macc   = (float*)(sm + 14336);
  float*    sacc   = (float*)(sm + 14464);
  unsigned* scnt   = (unsigned*)(sm + 16384);
  unsigned* ldone  = (unsigned*)(sm + 20480);
  unsigned* mdone  = (unsigned*)(sm + 24576);

  unsigned* hist = (unsigned*)(ws + OFF_HIST);
  unsigned long long* surv = (unsigned long long*)(ws + OFF_SURV);
  unsigned* sel  = (unsigned*)(ws + OFF_SEL);
  unsigned long long* bnd = (unsigned long long*)(ws + OFF_BND);
  float2* pp = (float2*)(ws + OFF_PP);
  float* wx = (float*)(ws + OFF_WXp);
  float* wy = (float*)(ws + OFF_WYp);
  float* lg = (float*)(ws + OFF_LG);
  float* sl = (float*)(ws + OFF_SL);
  float* pmin = (float*)(ws + OFF_PMIN);

  float* out = (float*)d_out;

  hipMemsetAsync(sm, 0, 32768, stream);

  // pass 1: exp + sume/sumS/Zb (separable conv sums via prefix diffs)
  k_pre<<<4096, 256, 0, stream>>>(scoremap, hd, A, sume, sumS, Zb);

  // matchability (interleaved b12, global-direct column conv)
  k_hconv<<<8192, 256, 0, stream>>>(A, hd, sume, B12);
  k_match<<<1024, 256, 0, stream>>>(B12, sume, sumS, Zb, macc);

  // coverage conv (h) -> B1p; hist zeroed inside k_h51 (B12 dead after k_match)
  k_h51<<<8192, 256, 0, stream>>>(A, sume, B1p, hist);

  // fused vconv+reweight+NMS+compaction+hist (R4-proven LDS-tiled version)
  k_smwnms<<<1024, 512, 0, stream>>>(A, sume, B1p, surv, scnt, hist);
  k_thresh<<<16, 1024, 0, stream>>>(hist, Tb, needb);
  k_collect<<<2048, 256, 0, stream>>>(surv, scnt, Tb, selcnt, sel, bcnt, bnd);
  k_finsel<<<16, 1024, 0, stream>>>(bnd, bcnt, needb, selcnt, sel);

  // sparse loss (loss + out folded into k_mindist via mdone/ldone counters)
  k_prep<<<128, 256, 0, stream>>>(sel, scoremap, gtA, gtB, vA, vB, pp, wx, wy, lg, sl);
  k_mindist<<<512, 256, 0, stream>>>(pp, wx, wy, pmin, sl, lg,
                                     sacc, macc, out, mdone, ldone);
}

// Round 11
// 285.925 us; speedup vs baseline: 1.0581x; 1.0581x over previous
//
#include <hip/hip_runtime.h>

#define HH 512
#define WW 512
#define HW_ 262144
#define NIMG 16
#define MK 2048
#define CAPB 4096
#define SCAP 32768   // survivor capacity per image
#define SBUFN 768    // per-block survivor staging (>=484 worst-case maxima per 64x64 tile)

static constexpr size_t OFF_B1    = 16777216;   // 16MB
static constexpr size_t OFF_SMALL = 50331648;   // 48MB
// regions inside buffer A (all written only after A's last read in k_smwnms):
static constexpr size_t OFF_SEL  = 4194304;
static constexpr size_t OFF_BND  = 4325376;
static constexpr size_t OFF_PP   = 4849664;
static constexpr size_t OFF_WXp  = 5111808;
static constexpr size_t OFF_WYp  = 5242880;
static constexpr size_t OFF_LG   = 5373952;
static constexpr size_t OFF_SL   = 5505024;
static constexpr size_t OFF_PMIN = 5636096;
// regions inside B12's upper half (dead after k_match):
static constexpr size_t OFF_HIST = 33554432;            // 4MB
static constexpr size_t OFF_SURV = 33554432 + 4194304;  // 4MB

// per-image counters padded to 128B to kill cacheline serialization
#define CSTRIDE 32

// ---------- helpers ----------
__device__ __forceinline__ float wred64(float v) {
  for (int m = 1; m < 64; m <<= 1) v += __shfl_xor(v, m);
  return v;
}

__device__ __forceinline__ void g25_wave0(float* g) {
  int t = threadIdx.x;
  if (t < 64) {
    float raw = 0.0f;
    if (t < 25) {
      float x = -1.0f + (float)t * (2.0f / 24.0f);
      raw = expf(-(x * x) / 0.5f);
    }
    float s = raw;
    for (int m = 1; m < 64; m <<= 1) s += __shfl_xor(s, m);
    if (t < 25) g[t] = raw / s;
  }
}
__device__ __forceinline__ void w51_wave0(float* wc) {
  int t = threadIdx.x;
  if (t < 51) {
    float x = -2.0f + (float)t * (4.0f / 50.0f);
    wc[t] = expf(-x * x);
  }
}

template<int B>
__device__ __forceinline__ float brsum(float v, float* red) {
  int t = threadIdx.x;
  red[t] = v; __syncthreads();
  for (int s = B >> 1; s > 0; s >>= 1) {
    if (t < s) red[t] += red[t + s];
    __syncthreads();
  }
  float r = red[0]; __syncthreads();
  return r;
}
template<int B>
__device__ __forceinline__ float brmax(float v, float* red) {
  int t = threadIdx.x;
  red[t] = v; __syncthreads();
  for (int s = B >> 1; s > 0; s >>= 1) {
    if (t < s) red[t] = fmaxf(red[t], red[t + s]);
    __syncthreads();
  }
  float r = red[0]; __syncthreads();
  return r;
}

// ---------- pass 1: exp + all three global sums (separable conv trick) ----------
// tap-range sums via prefix differences (gp[hi+1]-gp[lo]) instead of per-thread loops
__global__ void __launch_bounds__(256)
k_pre(const float* __restrict__ x, const float* __restrict__ hd, float* A,
      float* sume, float* sumS, float* Zb) {
  __shared__ float g[25];
  __shared__ float gp[26];
  __shared__ float red[12];
  int tid = threadIdx.x;
  g25_wave0(g);
  if (tid == 0) {
    float c = 0.0f;
    gp[0] = 0.0f;
    for (int k = 0; k < 25; k++) { c += g[k]; gp[k + 1] = c; }
  }
  size_t base = (size_t)blockIdx.x * 1024;
  size_t e = base + tid * 4;
  float4 xs = *(const float4*)(x + e);
  float4 hs = *(const float4*)(hd + e);
  __syncthreads();
  int rem = (int)(e & (HW_ - 1));
  int y = rem >> 9, x0 = rem & 511;
  float wv;
  {
    int k0 = y - 499; if (k0 < 0) k0 = 0;
    int k1 = y + 12;  if (k1 > 24) k1 = 24;
    wv = gp[k1 + 1] - gp[k0];
  }
  float cwv[4], cpv[4];
#pragma unroll
  for (int q = 0; q < 4; q++) {
    int i = x0 + q;
    int lo = i - 487; if (lo < 0) lo = 0;
    int hi = i;       if (hi > 24) hi = 24;
    cwv[q] = gp[hi + 1] - gp[lo];
    int lo2 = i - 499; if (lo2 < 0) lo2 = 0;
    int hi2 = i + 12;  if (hi2 > 24) hi2 = 24;
    cpv[q] = gp[hi2 + 1] - gp[lo2];
  }
  float e0 = expf(xs.x), e1 = expf(xs.y), e2 = expf(xs.z), e3 = expf(xs.w);
  *(float4*)(A + e) = make_float4(e0, e1, e2, e3);
  float r0 = (e0 + e1) + (e2 + e3);
  float r1 = (e0 * cwv[0] + e1 * cwv[1] + e2 * cwv[2] + e3 * cwv[3]) * wv;
  float r2 = (hs.x * cpv[0] + hs.y * cpv[1] + hs.z * cpv[2] + hs.w * cpv[3]) * wv;
  r0 = wred64(r0); r1 = wred64(r1); r2 = wred64(r2);
  int wid = tid >> 6;
  if ((tid & 63) == 0) { red[wid] = r0; red[4 + wid] = r1; red[8 + wid] = r2; }
  __syncthreads();
  if (tid == 0) {
    int img = (int)(base >> 18);
    atomicAdd(&sume[img * CSTRIDE], red[0] + red[1] + red[2] + red[3]);
    atomicAdd(&sumS[img * CSTRIDE], red[4] + red[5] + red[6] + red[7]);
    atomicAdd(&Zb[img * CSTRIDE], red[8] + red[9] + red[10] + red[11]);
  }
}

// ---------- horizontal convs: pure streaming, one row per block ----------
// writes interleaved {b1,b2} pairs -> single dwordx4 store per thread
__global__ void __launch_bounds__(256)
k_hconv(const float* __restrict__ A, const float* __restrict__ hd,
        const float* __restrict__ sume, float* b12) {
  __shared__ __align__(16) float ta[512];
  __shared__ __align__(16) float th[536];
  __shared__ float g[25];
  int tid = threadIdx.x;
  int blk = blockIdx.x;
  int img = blk >> 9;
  size_t rowoff = (size_t)blk * 512;
  g25_wave0(g);
  ((float2*)ta)[tid] = *(const float2*)(A + rowoff + tid * 2);
  ((float2*)(th + 12))[tid] = *(const float2*)(hd + rowoff + tid * 2);
  if (tid < 12) { th[tid] = 0.0f; th[524 + tid] = 0.0f; }
  __syncthreads();
  float inv = 1.0f / sume[img * CSTRIDE];
  int j = 2 * tid;
  float v1a = 0.0f, v1b = 0.0f;
  if (tid >= 6 && tid <= 249) {
    float w[26];
#pragma unroll
    for (int d = 0; d < 26; d++) w[d] = ta[j - 12 + d];
#pragma unroll
    for (int d = 0; d < 25; d++) {
      v1a = fmaf(g[d], w[d], v1a);
      v1b = fmaf(g[d], w[d + 1], v1b);
    }
  }
  float v2a = 0.0f, v2b = 0.0f;
  {
    float u[26];
#pragma unroll
    for (int d = 0; d < 26; d++) u[d] = th[j + d];
#pragma unroll
    for (int d = 0; d < 25; d++) {
      v2a = fmaf(g[d], u[d], v2a);
      v2b = fmaf(g[d], u[d + 1], v2b);
    }
  }
  // pixel pair (j, j+1): interleaved {b1,b2} per pixel
  *(float4*)(b12 + (rowoff + j) * 2) =
      make_float4(v1a * inv, v2a, v1b * inv, v2b);
}

// fused vertical convs + KL reduction — global-direct column conv.
// Each thread owns one column x 16 output rows; the 25-tap window slides
// down the column in registers (rolling 16-reg weight window, zero-padded
// taps keep fmaf order bit-identical to the tiled version). No LDS tile.
__global__ void __launch_bounds__(256)
k_match(const float* __restrict__ b12,
        const float* __restrict__ sume, const float* sumS, const float* Zb,
        float* macc) {
  __shared__ float g[40];                      // taps 0..24 real, 25..39 = 0
  __shared__ float red4[4];
  int tid = threadIdx.x;
  g25_wave0(g);
  if (tid >= 25 && tid < 40) g[tid] = 0.0f;
  int blk = blockIdx.x;
  int img = blk >> 6;
  int ty = (blk >> 3) & 7;
  int tx = blk & 7;
  int y0 = ty * 64, x0 = tx * 64;
  const float* base12 = b12 + (size_t)img * HW_ * 2;
  float Z = Zb[img * CSTRIDE];
  float invs = 1.0f / sume[img * CSTRIDE];
  float logS = logf(sumS[img * CSTRIDE] * invs + (float)HW_ * 1e-8f);
  __syncthreads();
  int seg = tid >> 6;        // 4 row segments of 16
  int c = tid & 63;
  int r0 = seg * 16;
  const float* colp = base12 + (size_t)(x0 + c) * 2;
  float s[16], d[16], wreg[16];
#pragma unroll
  for (int jj = 0; jj < 16; jj++) { s[jj] = 0.f; d[jj] = 0.f; wreg[jj] = 0.f; }
  int ybase = y0 + r0 - 12;
#pragma unroll
  for (int i = 0; i < 40; i++) {
    int y = ybase + i;
    float vx = 0.0f, vy = 0.0f;
    if ((unsigned)y < 512u) {                   // wave-uniform
      float2 v = *(const float2*)(colp + (size_t)y * 1024);
      vx = v.x; vy = v.y;
    }
#pragma unroll
    for (int jj = 15; jj >= 1; jj--) wreg[jj] = wreg[jj - 1];
    wreg[0] = g[i];
#pragma unroll
    for (int jj = 0; jj < 16; jj++) {
      s[jj] = fmaf(wreg[jj], vx, s[jj]);
      d[jj] = fmaf(wreg[jj], vy, d[jj]);
    }
  }
  float acc = 0.0f;
#pragma unroll
  for (int jj = 0; jj < 16; jj++) {
    float p = d[jj] / Z;
    if (p > 0.0f)
      acc += p * (logf(fmaxf(p, 1e-30f)) - (logf(s[jj] + 1e-8f) - logS));
  }
  acc = wred64(acc);
  if ((tid & 63) == 0) red4[tid >> 6] = acc;
  __syncthreads();
  if (tid == 0)
    atomicAdd(macc, red4[0] + red4[1] + red4[2] + red4[3]);
}

// ---------- keypoint sampling ----------
// also zeroes 512B of hist per block (replaces the 4MB memset dispatch)
__global__ void __launch_bounds__(256)
k_h51(const float* __restrict__ A, const float* __restrict__ sume, float* out,
      unsigned* __restrict__ hist) {
  __shared__ float wc[51];
  __shared__ __align__(16) float ta[564];
  int tid = threadIdx.x;
  int blk = blockIdx.x;
  int img = blk >> 9;
  size_t rowoff = (size_t)blk * 512;
  w51_wave0(wc);
  if (tid < 32)
    ((uint4*)hist)[(size_t)blk * 32 + tid] = make_uint4(0u, 0u, 0u, 0u);
  float s1 = 1e4f / sume[img * CSTRIDE];
  for (int i = tid; i < 562; i += 256) {
    int j = i - 25;
    ta[i] = ((unsigned)j < 512u) ? fmaf(A[rowoff + j], s1, 1e-2f) : 0.0f;
  }
  __syncthreads();
  int j = 2 * tid;
  float w[52];
#pragma unroll
  for (int d = 0; d < 52; d++) w[d] = ta[j + d];
  float va = 0.0f, vb = 0.0f;
#pragma unroll
  for (int d = 0; d < 51; d++) {
    va = fmaf(wc[d], w[d], va);
    vb = fmaf(wc[d], w[d + 1], vb);
  }
  ((float2*)out)[blk * 256 + tid] = make_float2(va, vb);
}

// fused: vertical 51-tap (register-tiled R=3 x C=4, float4 LDS) + coverage
// reweight + separable 5x5 NMS (float4) + block-aggregated survivor
// compaction + histogram.  [R2/R4/R9-proven version: ~49us, 40 VGPR, no spill]
__global__ void __launch_bounds__(512, 6)
k_smwnms(const float* __restrict__ A, const float* __restrict__ sume,
         const float* __restrict__ b1,
         unsigned long long* surv, unsigned* scnt, unsigned* hist) {
  __shared__ float wc[53];                     // taps 0..50 real, 51..52 = 0
  __shared__ __align__(16) float tb1[119 * 68];
  __shared__ __align__(16) float tsm[68 * 68];
  __shared__ unsigned lcnt;
  __shared__ unsigned gbase;
  float* hm = tb1;  // alias: tb1 dead after conv phase; hm is 68x64 = floats [0,4352)
  unsigned long long* sbuf = (unsigned long long*)(tb1 + 4352);
  int tid = threadIdx.x;
  w51_wave0(wc);
  if (tid == 51 || tid == 52) wc[tid] = 0.0f;
  if (tid == 0) lcnt = 0;
  int blk = blockIdx.x;
  int img = blk >> 6;
  int ty = (blk >> 3) & 7;
  int tx = blk & 7;
  int y0 = ty * 64, x0 = tx * 64;
  const float* base = b1 + (size_t)img * HW_;
  {
    float2 vreg[8];
    int laddr[8];
#pragma unroll
    for (int k = 0; k < 8; k++) {
      int i = tid + k * 512;
      bool ok = (i < 119 * 34);
      int r = i / 34, c2 = i - r * 34;
      int y = y0 + r - 27;
      int x = x0 + c2 * 2 - 2;
      float2 v = make_float2(0.0f, 0.0f);
      if (ok && (unsigned)y < 512u && (unsigned)x < 512u)
        v = *(const float2*)(base + (size_t)y * 512 + x);
      vreg[k] = v;
      laddr[k] = ok ? (r * 68 + c2 * 2) : -1;
    }
#pragma unroll
    for (int k = 0; k < 8; k++)
      if (laddr[k] >= 0) *(float2*)(tb1 + laddr[k]) = vreg[k];
  }
  __syncthreads();
  float inv = 1.0f / sume[img * CSTRIDE];
  const float* abase = A + (size_t)img * HW_;
  if (tid < 23 * 17) {
    int rg = tid / 17, cg = tid - rg * 17;
    int r0 = rg * 3, c0 = cg * 4;
    int nr = (r0 <= 65) ? 3 : 2;  // rg=22 -> output rows 66,67 only
    float2 apre[3][2];
#pragma unroll
    for (int jj = 0; jj < 3; jj++) {
      int y = y0 + r0 + jj - 2;
      int xb = x0 + c0 - 2;
      apre[jj][0] = make_float2(0.f, 0.f);
      apre[jj][1] = make_float2(0.f, 0.f);
      if ((unsigned)y < 512u) {
        const float* ar = abase + (size_t)y * 512;
        if ((unsigned)xb < 512u) apre[jj][0] = *(const float2*)(ar + xb);
        if ((unsigned)(xb + 2) < 512u) apre[jj][1] = *(const float2*)(ar + xb + 2);
      }
    }
    float a0x = 0.f, a0y = 0.f, a0z = 0.f, a0w = 0.f;
    float a1x = 0.f, a1y = 0.f, a1z = 0.f, a1w = 0.f;
    float a2x = 0.f, a2y = 0.f, a2z = 0.f, a2w = 0.f;
    float w1 = 0.f, w2 = 0.f;
    const float* tp = tb1 + r0 * 68 + c0;
#pragma unroll 4
    for (int i = 0; i < 53; i++) {
      float4 v = *(const float4*)(tp + i * 68);
      float w0 = wc[i];
      a0x = fmaf(w0, v.x, a0x); a0y = fmaf(w0, v.y, a0y);
      a0z = fmaf(w0, v.z, a0z); a0w = fmaf(w0, v.w, a0w);
      a1x = fmaf(w1, v.x, a1x); a1y = fmaf(w1, v.y, a1y);
      a1z = fmaf(w1, v.z, a1z); a1w = fmaf(w1, v.w, a1w);
      a2x = fmaf(w2, v.x, a2x); a2y = fmaf(w2, v.y, a2y);
      a2z = fmaf(w2, v.z, a2z); a2w = fmaf(w2, v.w, a2w);
      w2 = w1; w1 = w0;
    }
    auto storerow = [&](int jj, float ax, float ay, float az, float aw,
                        float2 p0, float2 p1) {
      int r = r0 + jj;
      int y = y0 + r - 2;
      int xb = x0 + c0 - 2;
      float4 res = make_float4(-3.4e38f, -3.4e38f, -3.4e38f, -3.4e38f);
      if ((unsigned)y < 512u) {
        if ((unsigned)xb < 512u) {
          res.x = (p0.x * inv) / sqrtf(ax + 1e-8f);
          res.y = (p0.y * inv) / sqrtf(ay + 1e-8f);
        }
        if ((unsigned)(xb + 2) < 512u) {
          res.z = (p1.x * inv) / sqrtf(az + 1e-8f);
          res.w = (p1.y * inv) / sqrtf(aw + 1e-8f);
        }
      }
      *(float4*)(tsm + r * 68 + c0) = res;
    };
    storerow(0, a0x, a0y, a0z, a0w, apre[0][0], apre[0][1]);
    storerow(1, a1x, a1y, a1z, a1w, apre[1][0], apre[1][1]);
    if (nr == 3) storerow(2, a2x, a2y, a2z, a2w, apre[2][0], apre[2][1]);
  }
  __syncthreads();
  for (int i = tid; i < 68 * 16; i += 512) {
    int r = i >> 4, cg = i & 15;
    const float* row = tsm + r * 68 + cg * 4;
    float4 v0 = *(const float4*)(row);
    float4 v1 = *(const float4*)(row + 4);
    float p01 = fmaxf(v0.x, v0.y), p12 = fmaxf(v0.y, v0.z);
    float p23 = fmaxf(v0.z, v0.w), p34 = fmaxf(v0.w, v1.x);
    float p45 = fmaxf(v1.x, v1.y), p56 = fmaxf(v1.y, v1.z);
    float m0 = fmaxf(fmaxf(p01, p23), v1.x);
    float m1 = fmaxf(fmaxf(p12, p34), v1.y);
    float m2 = fmaxf(fmaxf(p23, p45), v1.z);
    float m3 = fmaxf(fmaxf(p34, p56), v1.w);
    *(float4*)(hm + r * 64 + cg * 4) = make_float4(m0, m1, m2, m3);
  }
  __syncthreads();
  for (int k0 = 0; k0 < 2; k0++) {
    int i = tid + k0 * 512;
    int r = i >> 4, cb = (i & 15) * 4;
    const float* tp2 = tsm + (r + 2) * 68 + cb + 2;
    float2 va = *(const float2*)(tp2);
    float2 vb = *(const float2*)(tp2 + 2);
    float4 m0 = *(const float4*)(hm + r * 64 + cb);
    float4 m1 = *(const float4*)(hm + (r + 1) * 64 + cb);
    float4 m2 = *(const float4*)(hm + (r + 2) * 64 + cb);
    float4 m3 = *(const float4*)(hm + (r + 3) * 64 + cb);
    float4 m4 = *(const float4*)(hm + (r + 4) * 64 + cb);
    float Mx = fmaxf(fmaxf(m0.x, m1.x), fmaxf(fmaxf(m2.x, m3.x), m4.x));
    float My = fmaxf(fmaxf(m0.y, m1.y), fmaxf(fmaxf(m2.y, m3.y), m4.y));
    float Mz = fmaxf(fmaxf(m0.z, m1.z), fmaxf(fmaxf(m2.z, m3.z), m4.z));
    float Mw = fmaxf(fmaxf(m0.w, m1.w), fmaxf(fmaxf(m2.w, m3.w), m4.w));
    auto keepf = [&](float vk, float Mk, int k) {
      if (vk == Mk && vk != 0.0f) {
        unsigned p = atomicAdd(&lcnt, 1u);   // LDS atomic: cheap
        unsigned bits = __float_as_uint(vk);
        unsigned idx = (unsigned)((y0 + r) * 512 + x0 + cb + k);
        if (p < SBUFN)
          sbuf[p] = ((unsigned long long)bits << 32) |
                    (unsigned long long)(idx ^ 0xFFFFFFFFu);
        atomicAdd(&hist[(size_t)img * 65536 + (bits >> 16)], 1u);
      }
    };
    keepf(va.x, Mx, 0); keepf(va.y, My, 1);
    keepf(vb.x, Mz, 2); keepf(vb.y, Mw, 3);
  }
  __syncthreads();
  unsigned total = lcnt; if (total > SBUFN) total = SBUFN;
  if (tid == 0) gbase = atomicAdd(&scnt[img * CSTRIDE], total);
  __syncthreads();
  unsigned gb = gbase;
  for (unsigned i = tid; i < total; i += 512) {
    unsigned p = gb + i;
    if (p < SCAP) surv[(size_t)img * SCAP + p] = sbuf[i];
  }
}

// 1024 threads, uint4 loads, shfl-scan
__global__ void __launch_bounds__(1024)
k_thresh(const unsigned* __restrict__ hist, unsigned* Tb, unsigned* needb) {
  int img = blockIdx.x;
  const unsigned* h = hist + (size_t)img * 65536;
  __shared__ unsigned wsum[16];
  __shared__ unsigned wpre[16];
  int t = threadIdx.x;  // thread t covers bins 65535-(t*64) .. 65472-(t*64)
  int b0 = 65472 - 64 * t;  // lowest bin of chunk (16B aligned)
  const uint4* hv = (const uint4*)(h + b0);
  unsigned s = 0;
#pragma unroll
  for (int k = 0; k < 16; k++) {
    uint4 u = hv[k];
    s += u.x + u.y + u.z + u.w;
  }
  if (b0 == 0) s += 0x00100000u - h[0];  // bin0 sentinel
  // inclusive wave scan over t (ascending t == descending bins)
  unsigned inc = s;
  for (int m = 1; m < 64; m <<= 1) {
    unsigned o = __shfl_up(inc, m);
    if ((t & 63) >= m) inc += o;
  }
  if ((t & 63) == 63) wsum[t >> 6] = inc;
  __syncthreads();
  if (t < 16) {
    unsigned p = 0;
    for (int k = 0; k < 16; k++) if (k < t) p += wsum[k];
    wpre[t] = p;
  }
  __syncthreads();
  unsigned pre = wpre[t >> 6] + inc - s;  // exclusive prefix of this chunk
  if (pre < MK && pre + s >= MK) {
    unsigned c = pre;
    for (int k = 0; k < 64; k++) {
      int bin = 65535 - (t * 64 + k);
      unsigned cnt = (bin == 0) ? 0x00100000u : h[bin];
      if (c + cnt >= MK) { Tb[img * CSTRIDE] = (unsigned)bin; needb[img * CSTRIDE] = MK - c; break; }
      c += cnt;
    }
  }
}

// compaction from survivor list
__global__ void k_collect(const unsigned long long* __restrict__ surv,
                          const unsigned* __restrict__ scnt,
                          const unsigned* __restrict__ Tb,
                          unsigned* selcnt, unsigned* sel,
                          unsigned* bcnt, unsigned long long* bnd) {
  int blk = blockIdx.x;
  int img = blk >> 7;
  int i = (blk & 127) * 256 + threadIdx.x;
  unsigned cnt = scnt[img * CSTRIDE]; if (cnt > SCAP) cnt = SCAP;
  unsigned long long entry = ((unsigned)i < cnt) ? surv[(size_t)img * SCAP + i] : 0ull;
  unsigned bits = (unsigned)(entry >> 32);
  unsigned bin = bits >> 16;
  unsigned T = Tb[img * CSTRIDE];
  bool ok = (unsigned)i < cnt;
  bool c1 = ok && (bin > T);
  bool c2 = ok && (bin == T);
  int lane = threadIdx.x & 63;
  unsigned long long lowmask = (1ull << lane) - 1ull;

  unsigned long long m1 = __ballot(c1);
  if (m1) {
    int leader = __ffsll(m1) - 1;
    unsigned base = 0;
    if (lane == leader) base = atomicAdd(&selcnt[img * CSTRIDE], (unsigned)__popcll(m1));
    base = __shfl(base, leader);
    if (c1) {
      unsigned p = base + (unsigned)__popcll(m1 & lowmask);
      if (p < MK) sel[img * MK + p] = (unsigned)(entry & 0xFFFFFFFFull) ^ 0xFFFFFFFFu;
    }
  }
  unsigned long long m2 = __ballot(c2);
  if (m2) {
    int leader = __ffsll(m2) - 1;
    unsigned base = 0;
    if (lane == leader) base = atomicAdd(&bcnt[img * CSTRIDE], (unsigned)__popcll(m2));
    base = __shfl(base, leader);
    if (c2) {
      unsigned p = base + (unsigned)__popcll(m2 & lowmask);
      if (p < CAPB) bnd[(size_t)img * CAPB + p] = entry;
    }
  }
}

__global__ void __launch_bounds__(1024)
k_finsel(const unsigned long long* __restrict__ bnd, const unsigned* bcnt,
         const unsigned* needb, const unsigned* selcnt, unsigned* sel) {
  int img = blockIdx.x;
  __shared__ unsigned long long key[CAPB];
  unsigned bn = bcnt[img * CSTRIDE];
  int n = (bn < CAPB) ? (int)bn : CAPB;
  int np2 = 2;
  while (np2 < n) np2 <<= 1;
  int t = threadIdx.x;
  for (int k = t; k < np2; k += 1024)
    key[k] = (k < n) ? bnd[(size_t)img * CAPB + k] : 0ull;
  __syncthreads();
  for (int sz = 2; sz <= np2; sz <<= 1) {
    for (int st = sz >> 1; st > 0; st >>= 1) {
      for (int i = t; i < np2; i += 1024) {
        int l = i ^ st;
        if (l > i) {
          unsigned long long a = key[i], b = key[l];
          bool up = ((i & sz) == 0);
          if (up ? (a < b) : (a > b)) { key[i] = b; key[l] = a; }
        }
      }
      __syncthreads();
    }
  }
  unsigned c1 = selcnt[img * CSTRIDE]; if (c1 > MK) c1 = MK;
  unsigned need = needb[img * CSTRIDE];
  unsigned kk = need; if (kk > MK - c1) kk = MK - c1;
  for (unsigned m = t; m < MK - c1; m += 1024) {
    unsigned v = 0u;
    if (m < kk && m < (unsigned)n)
      v = (unsigned)(key[m] & 0xFFFFFFFFull) ^ 0xFFFFFFFFu;
    sel[img * MK + c1 + m] = v;
  }
}

// ---------- sparse loss ----------
__global__ void k_prep(const unsigned* __restrict__ sel, const float* __restrict__ scoremap,
                       const float* __restrict__ gtA, const float* __restrict__ gtB,
                       const float* __restrict__ vA, const float* __restrict__ vB,
                       float2* pp, float* wx, float* wy, float* lg, float* sl) {
  int t = blockIdx.x * 256 + threadIdx.x;  // 0..32767
  int img = t >> 11;
  unsigned idx = sel[t] & (HW_ - 1);
  int h = idx >> 9, w = idx & 511;
  pp[t] = make_float2((w + 0.5f) * (2.0f / 512.0f) - 1.0f,
                      (h + 0.5f) * (2.0f / 512.0f) - 1.0f);
  int b = (img < 8) ? img : img - 8;
  const float* gt = (img < 8) ? gtA : gtB;
  const float* vv = (img < 8) ? vA : vB;
  size_t pix = (size_t)b * HW_ + idx;
  float2 gxy = *(const float2*)(gt + pix * 4 + 2);
  wx[t] = gxy.x;
  wy[t] = gxy.y;
  lg[t] = (vv[pix] > 0.0f) ? 1.0f : 0.0f;
  sl[t] = scoremap[(size_t)img * HW_ + idx];
}

// split 4-way over opponents, 8 independent min accumulators per thread
__global__ void __launch_bounds__(256)
k_mindist(const float2* __restrict__ pp,
          const float* __restrict__ wx, const float* __restrict__ wy,
          float* pmin) {
  __shared__ float2 opp[512];
  int blk = blockIdx.x;
  int img = blk >> 5;
  int qc = (blk >> 2) & 7;
  int oc = blk & 3;
  const float2* ob = pp + (size_t)(img ^ 8) * MK + oc * 512;
  for (int k = threadIdx.x; k < 512; k += 256) opp[k] = ob[k];
  __syncthreads();
  int m = img * MK + qc * 256 + threadIdx.x;
  float ax = wx[m], ay = wy[m];
  float d[8];
#pragma unroll
  for (int u = 0; u < 8; u++) d[u] = 3.4e38f;
  for (int n = 0; n < 512; n += 8) {
#pragma unroll
    for (int u = 0; u < 8; u++) {
      float2 o = opp[n + u];
      float dx = ax - o.x, dy = ay - o.y;
      d[u] = fminf(d[u], fmaf(dx, dx, dy * dy));
    }
  }
  float d2 = fminf(fminf(fminf(d[0], d[1]), fminf(d[2], d[3])),
                   fminf(fminf(d[4], d[5]), fminf(d[6], d[7])));
  pmin[oc * (NIMG * MK) + m] = d2;
}

// final block also writes the output scalar (replaces k_out dispatch)
__global__ void __launch_bounds__(1024)
k_loss(const float* __restrict__ sl, const float* __restrict__ lg,
       const float* __restrict__ pmin, float* sacc, float* macc, float* out,
       unsigned* ldone) {
  int img = blockIdx.x;
  __shared__ float red[1024];
  int t = threadIdx.x;
  int i0 = img * MK + t, i1 = i0 + 1024;
  float s0 = sl[i0], s1 = sl[i1];
  float g0 = lg[i0], g1 = lg[i1];
  float l0 = (g0 > 0.0f) ? s0 : -1e9f;
  float l1 = (g1 > 0.0f) ? s1 : -1e9f;
  float mx = brmax<1024>(fmaxf(l0, l1), red);
  float se = brsum<1024>(expf(l0 - mx) + expf(l1 - mx), red);
  float lse = mx + logf(se);
  const int ST = NIMG * MK;
  float a = 0.0f;
  if (g0 > 0.0f) {
    float mn = fminf(fminf(pmin[i0], pmin[ST + i0]),
                     fminf(pmin[2 * ST + i0], pmin[3 * ST + i0]));
    float r0 = expf(-100.0f * sqrtf(mn + 1e-12f));
    a += r0 * (s0 - lse);
  }
  if (g1 > 0.0f) {
    float mn = fminf(fminf(pmin[i1], pmin[ST + i1]),
                     fminf(pmin[2 * ST + i1], pmin[3 * ST + i1]));
    float r1 = expf(-100.0f * sqrtf(mn + 1e-12f));
    a += r1 * (s1 - lse);
  }
  float tot = brsum<1024>(a, red);
  if (t == 0) {
    atomicAdd(sacc, -tot);
    __threadfence();
    unsigned dnum = atomicAdd(ldone, 1u);
    if (dnum == NIMG - 1) {
      float sv = atomicAdd(sacc, 0.0f);   // L2-coherent reads
      float mv = atomicAdd(macc, 0.0f);
      out[0] = sv + mv * (1.0f / 16.0f);
    }
  }
}

// ---------- launch ----------
extern "C" void kernel_launch(void* const* d_in, const int* in_sizes, int n_in,
                              void* d_out, int out_size, void* d_ws, size_t ws_size,
                              hipStream_t stream) {
  const float* scoremap = (const float*)d_in[0];
  const float* gtA = (const float*)d_in[1];
  const float* gtB = (const float*)d_in[2];
  const float* vA  = (const float*)d_in[3];
  const float* vB  = (const float*)d_in[4];
  const float* hd  = (const float*)d_in[5];

  char* ws = (char*)d_ws;
  float* A   = (float*)(ws);
  float* B12 = (float*)(ws + OFF_B1);   // interleaved {b1,b2}, 32MB [16,48)
  float* B1p = (float*)(ws + OFF_B1);   // h51 output, 16MB (after k_match)

  char* sm = ws + OFF_SMALL;
  float*    sume   = (float*)(sm + 0);
  float*    sumS   = (float*)(sm + 2048);
  float*    Zb     = (float*)(sm + 4096);
  unsigned* Tb     = (unsigned*)(sm + 6144);
  unsigned* needb  = (unsigned*)(sm + 8192);
  unsigned* selcnt = (unsigned*)(sm + 10240);
  unsigned* bcnt   = (unsigned*)(sm + 12288);
  float*    macc   = (float*)(sm + 14336);
  float*    sacc   = (float*)(sm + 14464);
  unsigned* scnt   = (unsigned*)(sm + 16384);
  unsigned* ldone  = (unsigned*)(sm + 20480);

  unsigned* hist = (unsigned*)(ws + OFF_HIST);
  unsigned long long* surv = (unsigned long long*)(ws + OFF_SURV);
  unsigned* sel  = (unsigned*)(ws + OFF_SEL);
  unsigned long long* bnd = (unsigned long long*)(ws + OFF_BND);
  float2* pp = (float2*)(ws + OFF_PP);
  float* wx = (float*)(ws + OFF_WXp);
  float* wy = (float*)(ws + OFF_WYp);
  float* lg = (float*)(ws + OFF_LG);
  float* sl = (float*)(ws + OFF_SL);
  float* pmin = (float*)(ws + OFF_PMIN);

  float* out = (float*)d_out;

  hipMemsetAsync(sm, 0, 32768, stream);

  // pass 1: exp + sume/sumS/Zb (separable conv sums via prefix diffs)
  k_pre<<<4096, 256, 0, stream>>>(scoremap, hd, A, sume, sumS, Zb);

  // matchability (interleaved b12, global-direct column conv)
  k_hconv<<<8192, 256, 0, stream>>>(A, hd, sume, B12);
  k_match<<<1024, 256, 0, stream>>>(B12, sume, sumS, Zb, macc);

  // coverage conv (h) -> B1p; hist zeroed inside k_h51 (B12 dead after k_match)
  k_h51<<<8192, 256, 0, stream>>>(A, sume, B1p, hist);

  // fused vconv+reweight+NMS+compaction+hist (R4-proven LDS-tiled version)
  k_smwnms<<<1024, 512, 0, stream>>>(A, sume, B1p, surv, scnt, hist);
  k_thresh<<<16, 1024, 0, stream>>>(hist, Tb, needb);
  k_collect<<<2048, 256, 0, stream>>>(surv, scnt, Tb, selcnt, sel, bcnt, bnd);
  k_finsel<<<16, 1024, 0, stream>>>(bnd, bcnt, needb, selcnt, sel);

  // sparse loss (k_out folded into k_loss via ldone counter)
  k_prep<<<128, 256, 0, stream>>>(sel, scoremap, gtA, gtB, vA, vB, pp, wx, wy, lg, sl);
  k_mindist<<<512, 256, 0, stream>>>(pp, wx, wy, pmin);
  k_loss<<<16, 1024, 0, stream>>>(sl, lg, pmin, sacc, macc, out, ldone);
}